// Round 6
// baseline (851.659 us; speedup 1.0000x reference)
//
#include <hip/hip_runtime.h>

using s8 = __attribute__((ext_vector_type(8))) short;
using f4 = __attribute__((ext_vector_type(4))) float;

constexpr int WIDTH   = 16;
constexpr int HID     = 512;
constexpr int NHEADS  = 8;
constexpr int DK      = 64;
constexpr int NLAYERS = 2;
constexpr int NHW     = 2;
constexpr int B       = 4;
constexpr int S       = 1024;
constexpr int PAD     = S + 2 * WIDTH;   // 1056
constexpr int RS      = 1024;            // split row stride (shorts): [H(512)|L(512)]

// Split-bf16 scheme: x = h + l (both bf16). Storage is 2-plane [H|L] per row.
// The GEMM K-loop (K2=1536) reads A as [H,L,H] and B as [H,H,L] via k0
// remapping, giving Ah*Bh + Al*Bh + Ah*Bl (drops only Al*Bl ~ 2^-18).
__device__ inline unsigned short f2bf(float x) {
    union { float f; unsigned u; } c; c.f = x;
    unsigned r = c.u + 0x7fffu + ((c.u >> 16) & 1u);
    return (unsigned short)(r >> 16);
}
__device__ inline float bf2f(unsigned short h) {
    union { float f; unsigned u; } c; c.u = ((unsigned)h) << 16; return c.f;
}
__device__ inline void split2(float x, unsigned short& h, unsigned short& l) {
    h = f2bf(x);
    l = f2bf(x - bf2f(h));
}
__device__ inline void store_split4(unsigned short* dst, float4 v) {
    unsigned short h[4], l[4];
    split2(v.x, h[0], l[0]); split2(v.y, h[1], l[1]);
    split2(v.z, h[2], l[2]); split2(v.w, h[3], l[3]);
    uint2 hp, lp;
    hp.x = h[0] | ((unsigned)h[1] << 16); hp.y = h[2] | ((unsigned)h[3] << 16);
    lp.x = l[0] | ((unsigned)l[1] << 16); lp.y = l[2] | ((unsigned)l[3] << 16);
    *(uint2*)(dst)       = hp;
    *(uint2*)(dst + 512) = lp;
}

// ---------------------------------------------------------------------------
// build padded sequence -> split acts [B*PAD, RS]; z selects direction slot
// ---------------------------------------------------------------------------
__global__ __launch_bounds__(256) void build_pad_split(
    const float* __restrict__ src0, const float* __restrict__ src1,
    const float* __restrict__ front, const float* __restrict__ back,
    unsigned short* __restrict__ d0, unsigned short* __restrict__ d1)
{
    const float* x = blockIdx.z ? src1 : src0;
    unsigned short* xp2 = blockIdx.z ? d1 : d0;
    int idx = blockIdx.x * 256 + threadIdx.x;   // over B*PAD*128
    int c4 = idx & 127;
    int rest = idx >> 7;
    int p = rest % PAD;
    int b = rest / PAD;
    float4 val;
    if (p < WIDTH) {
        val = *(const float4*)(front + (size_t)p * HID + c4 * 4);
    } else if (p < WIDTH + S) {
        val = *(const float4*)(x + ((size_t)b * S + (p - WIDTH)) * HID + c4 * 4);
    } else {
        val = *(const float4*)(back + (size_t)(p - WIDTH - S) * HID + c4 * 4);
    }
    store_split4(xp2 + (size_t)(b * PAD + p) * RS + c4 * 4, val);
}

// ---------------------------------------------------------------------------
// weights fp32 [R, HID] -> split [R, RS]
// ---------------------------------------------------------------------------
__global__ __launch_bounds__(256) void conv_w(
    const float* __restrict__ s0, const float* __restrict__ s1,
    unsigned short* __restrict__ w0, unsigned short* __restrict__ w1)
{
    const float* src = blockIdx.z ? s1 : s0;
    unsigned short* dst = blockIdx.z ? w1 : w0;
    int idx = blockIdx.x * 256 + threadIdx.x;   // over R*128
    int c4 = idx & 127;
    int r  = idx >> 7;
    float4 v = *(const float4*)(src + (size_t)r * HID + c4 * 4);
    store_split4(dst + (size_t)r * RS + c4 * 4, v);
}

// ---------------------------------------------------------------------------
// Split-bf16 MFMA GEMM (NT): C = A*B^T + bias over virtual K2=1536.
// A segs [H,L,H]: aoff = k0<1024 ? k0 : k0-1024
// B segs [H,H,L]: boff = k0<512  ? k0 : k0-512
// LDS tiles are GRANULE-MAJOR [4 granules][128 rows][8 shorts] so fragment
// ds_read_b128 is conflict-free (R5: row-major layout gave 8-way conflicts,
// 4.87M SQ_LDS_BANK_CONFLICT/dispatch). Staging: wave w loads k-granule w
// of all 128 rows (lane=row, 2 chunks), LDS fills linearly (wave-uniform
// base + lane*16 satisfied), global pointer absorbs the permutation.
// ---------------------------------------------------------------------------
__global__ __launch_bounds__(256) void gemm_split(
    const unsigned short* __restrict__ A0, const unsigned short* __restrict__ B0,
    const float* __restrict__ bias0, float* __restrict__ C0,
    const unsigned short* __restrict__ A1, const unsigned short* __restrict__ B1,
    const float* __restrict__ bias1, float* __restrict__ C1,
    int N)
{
    const unsigned short* A  = blockIdx.z ? A1 : A0;
    const unsigned short* Bw = blockIdx.z ? B1 : B0;
    const float* bias        = blockIdx.z ? bias1 : bias0;
    float* C                 = blockIdx.z ? C1 : C0;

    __shared__ unsigned short Als[128 * 32];
    __shared__ unsigned short Bls[128 * 32];

    const int tid  = threadIdx.x;
    const int wave = tid >> 6;
    const int lane = tid & 63;
    const int bm = blockIdx.y * 128;
    const int bn = blockIdx.x * 128;
    const int wm = (wave >> 1) * 64;
    const int wn = (wave & 1) * 64;

    // staging: wave stages granule `wave` (8 shorts at k-offset wave*8) for
    // rows [0,64) and [64,128). LDS chunk for (granule g, rowhalf h) is
    // (g*2 + h)*512 shorts; within it lane l holds row h*64+l.
    const unsigned short* Aga = A  + (size_t)(bm + lane) * RS + wave * 8;
    const unsigned short* Agb = A  + (size_t)(bm + 64 + lane) * RS + wave * 8;
    const unsigned short* Bga = Bw + (size_t)(bn + lane) * RS + wave * 8;
    const unsigned short* Bgb = Bw + (size_t)(bn + 64 + lane) * RS + wave * 8;
    const int ls0 = (wave * 2 + 0) * 512;
    const int ls1 = (wave * 2 + 1) * 512;

    f4 acc[4][4] = {};

    for (int k0 = 0; k0 < 1536; k0 += 32) {
        const int aoff = (k0 < 1024) ? k0 : (k0 - 1024);
        const int boff = (k0 < 512)  ? k0 : (k0 - 512);
        __builtin_amdgcn_global_load_lds(
            (const __attribute__((address_space(1))) void*)(Aga + aoff),
            (__attribute__((address_space(3))) void*)&Als[ls0], 16, 0, 0);
        __builtin_amdgcn_global_load_lds(
            (const __attribute__((address_space(1))) void*)(Agb + aoff),
            (__attribute__((address_space(3))) void*)&Als[ls1], 16, 0, 0);
        __builtin_amdgcn_global_load_lds(
            (const __attribute__((address_space(1))) void*)(Bga + boff),
            (__attribute__((address_space(3))) void*)&Bls[ls0], 16, 0, 0);
        __builtin_amdgcn_global_load_lds(
            (const __attribute__((address_space(1))) void*)(Bgb + boff),
            (__attribute__((address_space(3))) void*)&Bls[ls1], 16, 0, 0);
        __syncthreads();

        // fragment read: granule q = lane>>4, row = tile-row; addr q*1024+row*8
        const int fr = lane & 15;
        const int q  = lane >> 4;
        s8 a[4], b[4];
        #pragma unroll
        for (int i = 0; i < 4; ++i)
            a[i] = *(const s8*)&Als[q * 1024 + (wm + i * 16 + fr) * 8];
        #pragma unroll
        for (int j = 0; j < 4; ++j)
            b[j] = *(const s8*)&Bls[q * 1024 + (wn + j * 16 + fr) * 8];
        #pragma unroll
        for (int i = 0; i < 4; ++i)
            #pragma unroll
            for (int j = 0; j < 4; ++j)
                acc[i][j] = __builtin_amdgcn_mfma_f32_16x16x32_bf16(
                    a[i], b[j], acc[i][j], 0, 0, 0);
        __syncthreads();
    }

    const int col = lane & 15;
    const int rb  = (lane >> 4) * 4;
    #pragma unroll
    for (int j = 0; j < 4; ++j) {
        float bj = bias[bn + wn + j * 16 + col];
        #pragma unroll
        for (int i = 0; i < 4; ++i) {
            size_t base = (size_t)(bm + wm + i * 16 + rb) * N + (bn + wn + j * 16 + col);
            #pragma unroll
            for (int r = 0; r < 4; ++r)
                C[base + (size_t)r * N] = acc[i][j][r] + bj;
        }
    }
}

// ---------------------------------------------------------------------------
// Banded MHA. One wave per (b,h,i). backward = dir0 + z.
// ---------------------------------------------------------------------------
__global__ __launch_bounds__(256) void banded_attn(
    const float* __restrict__ Q0, const float* __restrict__ Q1,
    unsigned short* __restrict__ O0, unsigned short* __restrict__ O1,
    int dir0)
{
    const float* QKV = blockIdx.z ? Q1 : Q0;
    unsigned short* O2 = blockIdx.z ? O1 : O0;
    int backward = dir0 + blockIdx.z;

    int w    = blockIdx.x * 4 + (threadIdx.x >> 6);
    int lane = threadIdx.x & 63;
    int i  = w % PAD;
    int bh = w / PAD;
    int h  = bh & (NHEADS - 1);
    int b  = bh / NHEADS;

    int jlo, n;
    if (backward) { jlo = i; n = min(WIDTH + 2, PAD - i); }
    else          { jlo = max(0, i - WIDTH - 1); n = i - jlo + 1; }

    const int s = lane >> 4;
    const int d = lane & 15;
    const size_t rowbase = (size_t)(b * PAD) * 1536;
    const int colq = h * DK;

    float4 q4 = *(const float4*)(QKV + rowbase + (size_t)i * 1536 + colq + 4 * d);

    float sc[5];
    #pragma unroll
    for (int m = 0; m < 5; ++m) {
        int t  = 4 * m + s;
        int tc = t < n ? t : n - 1;
        float4 kv = *(const float4*)(QKV + rowbase + (size_t)(jlo + tc) * 1536
                                     + 512 + colq + 4 * d);
        float p = q4.x * kv.x + q4.y * kv.y + q4.z * kv.z + q4.w * kv.w;
        p += __shfl_xor(p, 1);
        p += __shfl_xor(p, 2);
        p += __shfl_xor(p, 4);
        p += __shfl_xor(p, 8);
        sc[m] = p * 0.125f;
    }

    float sv[WIDTH + 2];
    #pragma unroll
    for (int t = 0; t < WIDTH + 2; ++t) {
        float v = __shfl(sc[t >> 2], (t & 3) << 4);
        sv[t] = (t < n) ? v : -1e30f;
    }
    float mx = sv[0];
    #pragma unroll
    for (int t = 1; t < WIDTH + 2; ++t) mx = fmaxf(mx, sv[t]);
    float denom = 0.f;
    #pragma unroll
    for (int t = 0; t < WIDTH + 2; ++t) { sv[t] = __expf(sv[t] - mx); denom += sv[t]; }
    float inv = 1.0f / denom;

    float od0 = 0.f, od1 = 0.f;
    #pragma unroll
    for (int t = 0; t < WIDTH + 2; t += 2) {
        int tc0 = t     < n ? t     : n - 1;
        int tc1 = t + 1 < n ? t + 1 : n - 1;
        od0 += sv[t]     * QKV[rowbase + (size_t)(jlo + tc0) * 1536 + 1024 + colq + lane];
        od1 += sv[t + 1] * QKV[rowbase + (size_t)(jlo + tc1) * 1536 + 1024 + colq + lane];
    }
    float od = (od0 + od1) * inv;

    unsigned short hh, ll;
    split2(od, hh, ll);
    size_t ro = (size_t)(b * PAD + i) * RS + colq + lane;
    O2[ro] = hh; O2[ro + 512] = ll;
}

// ---------------------------------------------------------------------------
// rel combine -> split acts
// ---------------------------------------------------------------------------
__global__ __launch_bounds__(256) void rel_combine(
    const float* __restrict__ a0, const float* __restrict__ a1,
    const float* __restrict__ w0, const float* __restrict__ w1,
    unsigned short* __restrict__ f0, unsigned short* __restrict__ f1,
    int off0, int off1)
{
    const float* att = blockIdx.z ? a1 : a0;
    const float* w   = blockIdx.z ? w1 : w0;
    unsigned short* fo2 = blockIdx.z ? f1 : f0;
    int offset = blockIdx.z ? off1 : off0;

    int idx = blockIdx.x * 256 + threadIdx.x;   // over B*S*128
    int c4 = idx & 127;
    int rest = idx >> 7;
    int t = rest & (S - 1);
    int b = rest >> 10;

    const float* rowbase = att + (size_t)b * PAD * HID + c4 * 4;
    float4 acc = *(const float4*)(rowbase + (size_t)(WIDTH + t) * HID);
    #pragma unroll
    for (int k = 0; k <= WIDTH; ++k) {
        float wk = w[k];
        float4 xv = *(const float4*)(rowbase + (size_t)(offset + k + t) * HID);
        acc.x += wk * xv.x; acc.y += wk * xv.y;
        acc.z += wk * xv.z; acc.w += wk * xv.w;
    }
    store_split4(fo2 + ((size_t)b * S + t) * RS + c4 * 4, acc);
}

// ---------------------------------------------------------------------------
// highway gate; x reconstructed from split acts (h+l)
// ---------------------------------------------------------------------------
__global__ __launch_bounds__(256) void highway_gate(
    const unsigned short* __restrict__ x0, const unsigned short* __restrict__ x1,
    const float* __restrict__ p0, const float* __restrict__ p1,
    float* __restrict__ of0, float* __restrict__ of1,
    unsigned short* __restrict__ o20, unsigned short* __restrict__ o21,
    float* __restrict__ os0, float* __restrict__ os1)
{
    const unsigned short* x2 = blockIdx.z ? x1 : x0;
    const float* proj        = blockIdx.z ? p1 : p0;
    float* outf              = blockIdx.z ? of1 : of0;
    unsigned short* out2     = blockIdx.z ? o21 : o20;
    float* oslice            = blockIdx.z ? os1 : os0;

    int idx = blockIdx.x * 256 + threadIdx.x;   // over B*S*128
    int c4 = idx & 127;
    int r  = idx >> 7;
    const unsigned short* xr = x2 + (size_t)r * RS + c4 * 4;
    uint2 hp = *(const uint2*)(xr);
    uint2 lp = *(const uint2*)(xr + 512);
    float4 xv;
    xv.x = bf2f((unsigned short)(hp.x & 0xffff)) + bf2f((unsigned short)(lp.x & 0xffff));
    xv.y = bf2f((unsigned short)(hp.x >> 16))    + bf2f((unsigned short)(lp.x >> 16));
    xv.z = bf2f((unsigned short)(hp.y & 0xffff)) + bf2f((unsigned short)(lp.y & 0xffff));
    xv.w = bf2f((unsigned short)(hp.y >> 16))    + bf2f((unsigned short)(lp.y >> 16));

    float4 nl = *(const float4*)(proj + (size_t)r * (2 * HID) + c4 * 4);
    float4 g  = *(const float4*)(proj + (size_t)r * (2 * HID) + HID + c4 * 4);
    float4 o;
    float sg;
    sg = 1.f / (1.f + __expf(-g.x)); o.x = sg * xv.x + (1.f - sg) * fmaxf(nl.x, 0.f);
    sg = 1.f / (1.f + __expf(-g.y)); o.y = sg * xv.y + (1.f - sg) * fmaxf(nl.y, 0.f);
    sg = 1.f / (1.f + __expf(-g.z)); o.z = sg * xv.z + (1.f - sg) * fmaxf(nl.z, 0.f);
    sg = 1.f / (1.f + __expf(-g.w)); o.w = sg * xv.w + (1.f - sg) * fmaxf(nl.w, 0.f);
    if (outf)   *(float4*)(outf + (size_t)idx * 4) = o;
    if (out2)   store_split4(out2 + (size_t)r * RS + c4 * 4, o);
    if (oslice) *(float4*)(oslice + (size_t)r * (2 * HID) + c4 * 4) = o;
}

// ---------------------------------------------------------------------------
extern "C" void kernel_launch(void* const* d_in, const int* in_sizes, int n_in,
                              void* d_out, int out_size, void* d_ws, size_t ws_size,
                              hipStream_t stream)
{
    const float* inputs   = (const float*)d_in[0];
    const float* fw_lin_w = (const float*)d_in[2];
    const float* fw_lin_b = (const float*)d_in[3];
    const float* bw_lin_w = (const float*)d_in[4];
    const float* bw_lin_b = (const float*)d_in[5];
    const float* fw_hw_w  = (const float*)d_in[6];
    const float* fw_hw_b  = (const float*)d_in[7];
    const float* bw_hw_w  = (const float*)d_in[8];
    const float* bw_hw_b  = (const float*)d_in[9];
    const float* fw_pad   = (const float*)d_in[10];
    const float* bw_pad   = (const float*)d_in[11];
    const float* fw_rel   = (const float*)d_in[12];
    const float* bw_rel   = (const float*)d_in[13];
    float* out = (float*)d_out;
    float* ws  = (float*)d_ws;

    const size_t BSH  = (size_t)B * S * HID;      // 2,097,152 floats
    const size_t QKVF = (size_t)B * PAD * 1536;   // 6,488,064 floats per dir
    const int MP = B * PAD;                       // 4224
    const int MS = B * S;                         // 4096

    const size_t GROUPED_BYTES = (size_t)18874368 * 4;
    const bool grouped = ws_size >= GROUPED_BYTES;
    const int G = grouped ? 2 : 1;

    float* f  = ws;
    float* bk = f + BSH;

    float* QKV[2]; float* ATT[2]; float* HWP[2];
    unsigned short* ACT2[2]; unsigned short* W2[2];
    if (grouped) {
        QKV[0] = ws;             QKV[1] = ws + QKVF;
        float* extra = ws + 2 * BSH;
        ATT[0] = extra;          ATT[1] = extra + (size_t)MP * HID;
        HWP[0] = extra;          HWP[1] = extra + (size_t)MS * 1024;
        unsigned short* a2 = (unsigned short*)(ws + 2 * QKVF);
        ACT2[0] = a2;            ACT2[1] = a2 + (size_t)MP * RS;
        unsigned short* w2 = a2 + 2 * (size_t)MP * RS;
        W2[0] = w2;              W2[1] = w2 + (size_t)1536 * RS;
    } else {
        float* qkvS = bk + BSH;
        QKV[0] = QKV[1] = qkvS;
        ATT[0] = ATT[1] = qkvS;
        HWP[0] = HWP[1] = qkvS;
        unsigned short* a2 = (unsigned short*)(qkvS + QKVF);
        ACT2[0] = ACT2[1] = a2;
        W2[0] = W2[1] = a2 + (size_t)MP * RS;
    }

    for (int l = 0; l < NLAYERS; ++l) {
        const float* LINW[2] = {fw_lin_w + (size_t)l * 4 * HID * HID,
                                bw_lin_w + (size_t)l * 4 * HID * HID};
        const float* LINB[2] = {fw_lin_b + (size_t)l * 4 * HID,
                                bw_lin_b + (size_t)l * 4 * HID};
        const float* HWW[2]  = {fw_hw_w + (size_t)l * NHW * 2 * HID * HID,
                                bw_hw_w + (size_t)l * NHW * 2 * HID * HID};
        const float* HWB[2]  = {fw_hw_b + (size_t)l * NHW * 2 * HID,
                                bw_hw_b + (size_t)l * NHW * 2 * HID};
        const float* RELW[2] = {fw_rel + (size_t)l * (WIDTH + 1),
                                bw_rel + (size_t)l * (WIDTH + 1)};
        const float* front = fw_pad + (size_t)l * WIDTH * HID;
        const float* back  = bw_pad + (size_t)l * WIDTH * HID;
        float* DST[2] = {f, bk};
        float* OSL[2] = {out + (size_t)l * B * S * 2 * HID,
                         out + (size_t)l * B * S * 2 * HID + HID};
        const float* SRC[2] = {(l == 0) ? inputs : f, (l == 0) ? inputs : bk};

        for (int d0 = 0; d0 < 2; d0 += G) {
            const int dB = (G == 2) ? 1 : d0;

            build_pad_split<<<dim3(MP * 128 / 256, 1, G), 256, 0, stream>>>(
                SRC[d0], SRC[dB], front, back, ACT2[0], ACT2[1]);

            conv_w<<<dim3(1536 * 128 / 256, 1, G), 256, 0, stream>>>(
                LINW[d0], LINW[dB], W2[0], W2[1]);
            gemm_split<<<dim3(1536 / 128, MP / 128, G), 256, 0, stream>>>(
                ACT2[0], W2[0], LINB[d0], QKV[0],
                ACT2[1], W2[1], LINB[dB], QKV[1], 1536);

            banded_attn<<<dim3(B * NHEADS * PAD / 4, 1, G), 256, 0, stream>>>(
                QKV[0], QKV[1], ACT2[0], ACT2[1], d0);

            conv_w<<<dim3(512 * 128 / 256, 1, G), 256, 0, stream>>>(
                LINW[d0] + 3 * (size_t)HID * HID, LINW[dB] + 3 * (size_t)HID * HID,
                W2[0], W2[1]);
            gemm_split<<<dim3(512 / 128, MP / 128, G), 256, 0, stream>>>(
                ACT2[0], W2[0], LINB[d0] + 3 * HID, ATT[0],
                ACT2[1], W2[1], LINB[dB] + 3 * HID, ATT[1], 512);

            rel_combine<<<dim3(MS * 128 / 256, 1, G), 256, 0, stream>>>(
                ATT[0], ATT[1], RELW[d0], RELW[dB], ACT2[0], ACT2[1],
                d0 * WIDTH, dB * WIDTH);

            for (int i = 0; i < NHW; ++i) {
                conv_w<<<dim3(1024 * 128 / 256, 1, G), 256, 0, stream>>>(
                    HWW[d0] + (size_t)i * 2 * HID * HID,
                    HWW[dB] + (size_t)i * 2 * HID * HID, W2[0], W2[1]);
                gemm_split<<<dim3(1024 / 128, MS / 128, G), 256, 0, stream>>>(
                    ACT2[0], W2[0], HWB[d0] + (size_t)i * 2 * HID, HWP[0],
                    ACT2[1], W2[1], HWB[dB] + (size_t)i * 2 * HID, HWP[1], 1024);
                const bool last = (i == NHW - 1);
                highway_gate<<<dim3(MS * 128 / 256, 1, G), 256, 0, stream>>>(
                    ACT2[0], ACT2[1], HWP[0], HWP[1],
                    last ? DST[d0] : (float*)nullptr,
                    last ? DST[dB] : (float*)nullptr,
                    last ? (unsigned short*)nullptr : ACT2[0],
                    last ? (unsigned short*)nullptr : ACT2[1],
                    last ? OSL[d0] : (float*)nullptr,
                    last ? OSL[dB] : (float*)nullptr);
            }
        }
    }
}

// Round 7
// 688.493 us; speedup vs baseline: 1.2370x; 1.2370x over previous
//
#include <hip/hip_runtime.h>

using s8 = __attribute__((ext_vector_type(8))) short;
using f4 = __attribute__((ext_vector_type(4))) float;

constexpr int WIDTH   = 16;
constexpr int HID     = 512;
constexpr int NHEADS  = 8;
constexpr int DK      = 64;
constexpr int NLAYERS = 2;
constexpr int NHW     = 2;
constexpr int B       = 4;
constexpr int S       = 1024;
constexpr int PAD     = S + 2 * WIDTH;   // 1056
constexpr int RS      = 1024;            // split row stride (shorts): [H(512)|L(512)]

// Split-bf16 scheme: x = h + l (both bf16). Storage is 2-plane [H|L] per row.
// The GEMM K-loop (K2=1536) reads A as [H,L,H] and B as [H,H,L] via k0
// remapping, giving Ah*Bh + Al*Bh + Ah*Bl (drops only Al*Bl ~ 2^-18).
__device__ inline unsigned short f2bf(float x) {
    union { float f; unsigned u; } c; c.f = x;
    unsigned r = c.u + 0x7fffu + ((c.u >> 16) & 1u);
    return (unsigned short)(r >> 16);
}
__device__ inline float bf2f(unsigned short h) {
    union { float f; unsigned u; } c; c.u = ((unsigned)h) << 16; return c.f;
}
__device__ inline void split2(float x, unsigned short& h, unsigned short& l) {
    h = f2bf(x);
    l = f2bf(x - bf2f(h));
}
__device__ inline void store_split4(unsigned short* dst, float4 v) {
    unsigned short h[4], l[4];
    split2(v.x, h[0], l[0]); split2(v.y, h[1], l[1]);
    split2(v.z, h[2], l[2]); split2(v.w, h[3], l[3]);
    uint2 hp, lp;
    hp.x = h[0] | ((unsigned)h[1] << 16); hp.y = h[2] | ((unsigned)h[3] << 16);
    lp.x = l[0] | ((unsigned)l[1] << 16); lp.y = l[2] | ((unsigned)l[3] << 16);
    *(uint2*)(dst)       = hp;
    *(uint2*)(dst + 512) = lp;
}

// ---------------------------------------------------------------------------
// build padded sequence -> split acts [B*PAD, RS]; z selects direction slot
// ---------------------------------------------------------------------------
__global__ __launch_bounds__(256) void build_pad_split(
    const float* __restrict__ src0, const float* __restrict__ src1,
    const float* __restrict__ front, const float* __restrict__ back,
    unsigned short* __restrict__ d0, unsigned short* __restrict__ d1)
{
    const float* x = blockIdx.z ? src1 : src0;
    unsigned short* xp2 = blockIdx.z ? d1 : d0;
    int idx = blockIdx.x * 256 + threadIdx.x;   // over B*PAD*128
    int c4 = idx & 127;
    int rest = idx >> 7;
    int p = rest % PAD;
    int b = rest / PAD;
    float4 val;
    if (p < WIDTH) {
        val = *(const float4*)(front + (size_t)p * HID + c4 * 4);
    } else if (p < WIDTH + S) {
        val = *(const float4*)(x + ((size_t)b * S + (p - WIDTH)) * HID + c4 * 4);
    } else {
        val = *(const float4*)(back + (size_t)(p - WIDTH - S) * HID + c4 * 4);
    }
    store_split4(xp2 + (size_t)(b * PAD + p) * RS + c4 * 4, val);
}

// ---------------------------------------------------------------------------
// weights fp32 [R, HID] -> split [R, RS]
// ---------------------------------------------------------------------------
__global__ __launch_bounds__(256) void conv_w(
    const float* __restrict__ s0, const float* __restrict__ s1,
    unsigned short* __restrict__ w0, unsigned short* __restrict__ w1)
{
    const float* src = blockIdx.z ? s1 : s0;
    unsigned short* dst = blockIdx.z ? w1 : w0;
    int idx = blockIdx.x * 256 + threadIdx.x;   // over R*128
    int c4 = idx & 127;
    int r  = idx >> 7;
    float4 v = *(const float4*)(src + (size_t)r * HID + c4 * 4);
    store_split4(dst + (size_t)r * RS + c4 * 4, v);
}

// ---------------------------------------------------------------------------
// Split-bf16 MFMA GEMM (NT): C = A*B^T + bias over virtual K2=1536.
// A segs [H,L,H]: aoff = k0<1024 ? k0 : k0-1024
// B segs [H,H,L]: boff = k0<512  ? k0 : k0-512
// Staging (R5 shape + slot permutation): chunk = 16 rows x 32 shorts; lane
// (r=lane>>2, j=lane&3) fetches granule kg=(j+(r>>1))&3 of row r -> 4 lanes
// still cover one 64B line (coalesced, R6 regression avoided) while the
// permuted slots make fragment ds_read_b128 2-way-per-bank only (free),
// fixing R5's 8-way conflicts (4.87M/dispatch). Fragment (fr,q) reads slot
// 4*fr + ((q-(fr>>1))&3): each 16-lane quarter hits every 4-bank group 2x.
// ---------------------------------------------------------------------------
__global__ __launch_bounds__(256) void gemm_split(
    const unsigned short* __restrict__ A0, const unsigned short* __restrict__ B0,
    const float* __restrict__ bias0, float* __restrict__ C0,
    const unsigned short* __restrict__ A1, const unsigned short* __restrict__ B1,
    const float* __restrict__ bias1, float* __restrict__ C1,
    int N)
{
    const unsigned short* A  = blockIdx.z ? A1 : A0;
    const unsigned short* Bw = blockIdx.z ? B1 : B0;
    const float* bias        = blockIdx.z ? bias1 : bias0;
    float* C                 = blockIdx.z ? C1 : C0;

    __shared__ unsigned short Als[128 * 32];
    __shared__ unsigned short Bls[128 * 32];

    const int tid  = threadIdx.x;
    const int wave = tid >> 6;
    const int lane = tid & 63;
    const int bm = blockIdx.y * 128;
    const int bn = blockIdx.x * 128;
    const int wm = (wave >> 1) * 64;
    const int wn = (wave & 1) * 64;

    // staging: chunks c0,c1 (16 rows each); lane covers row lr, granule kg
    const int c0 = wave * 2, c1 = wave * 2 + 1;
    const int lr = lane >> 2;                      // row within chunk 0..15
    const int kg = ((lane & 3) + (lr >> 1)) & 3;   // permuted k-granule
    const int sr0 = c0 * 16 + lr;
    const int sr1 = c1 * 16 + lr;
    const int sc  = kg * 8;
    const unsigned short* Ag0 = A  + (size_t)(bm + sr0) * RS + sc;
    const unsigned short* Ag1 = A  + (size_t)(bm + sr1) * RS + sc;
    const unsigned short* Bg0 = Bw + (size_t)(bn + sr0) * RS + sc;
    const unsigned short* Bg1 = Bw + (size_t)(bn + sr1) * RS + sc;
    const int ls0 = c0 * 512;
    const int ls1 = c1 * 512;

    // fragment read slot (shorts offset within a 512-short chunk)
    const int fr = lane & 15;
    const int q  = lane >> 4;
    const int rslot = (4 * fr + ((q - (fr >> 1)) & 3)) * 8;

    f4 acc[4][4] = {};

    for (int k0 = 0; k0 < 1536; k0 += 32) {
        const int aoff = (k0 < 1024) ? k0 : (k0 - 1024);
        const int boff = (k0 < 512)  ? k0 : (k0 - 512);
        __builtin_amdgcn_global_load_lds(
            (const __attribute__((address_space(1))) void*)(Ag0 + aoff),
            (__attribute__((address_space(3))) void*)&Als[ls0], 16, 0, 0);
        __builtin_amdgcn_global_load_lds(
            (const __attribute__((address_space(1))) void*)(Ag1 + aoff),
            (__attribute__((address_space(3))) void*)&Als[ls1], 16, 0, 0);
        __builtin_amdgcn_global_load_lds(
            (const __attribute__((address_space(1))) void*)(Bg0 + boff),
            (__attribute__((address_space(3))) void*)&Bls[ls0], 16, 0, 0);
        __builtin_amdgcn_global_load_lds(
            (const __attribute__((address_space(1))) void*)(Bg1 + boff),
            (__attribute__((address_space(3))) void*)&Bls[ls1], 16, 0, 0);
        __syncthreads();

        s8 a[4], b[4];
        #pragma unroll
        for (int i = 0; i < 4; ++i)
            a[i] = *(const s8*)&Als[((wm >> 4) + i) * 512 + rslot];
        #pragma unroll
        for (int j = 0; j < 4; ++j)
            b[j] = *(const s8*)&Bls[((wn >> 4) + j) * 512 + rslot];
        #pragma unroll
        for (int i = 0; i < 4; ++i)
            #pragma unroll
            for (int j = 0; j < 4; ++j)
                acc[i][j] = __builtin_amdgcn_mfma_f32_16x16x32_bf16(
                    a[i], b[j], acc[i][j], 0, 0, 0);
        __syncthreads();
    }

    const int col = lane & 15;
    const int rb  = (lane >> 4) * 4;
    #pragma unroll
    for (int j = 0; j < 4; ++j) {
        float bj = bias[bn + wn + j * 16 + col];
        #pragma unroll
        for (int i = 0; i < 4; ++i) {
            size_t base = (size_t)(bm + wm + i * 16 + rb) * N + (bn + wn + j * 16 + col);
            #pragma unroll
            for (int r = 0; r < 4; ++r)
                C[base + (size_t)r * N] = acc[i][j][r] + bj;
        }
    }
}

// ---------------------------------------------------------------------------
// Banded MHA. One wave per (b,h,i). backward = dir0 + z.
// ---------------------------------------------------------------------------
__global__ __launch_bounds__(256) void banded_attn(
    const float* __restrict__ Q0, const float* __restrict__ Q1,
    unsigned short* __restrict__ O0, unsigned short* __restrict__ O1,
    int dir0)
{
    const float* QKV = blockIdx.z ? Q1 : Q0;
    unsigned short* O2 = blockIdx.z ? O1 : O0;
    int backward = dir0 + blockIdx.z;

    int w    = blockIdx.x * 4 + (threadIdx.x >> 6);
    int lane = threadIdx.x & 63;
    int i  = w % PAD;
    int bh = w / PAD;
    int h  = bh & (NHEADS - 1);
    int b  = bh / NHEADS;

    int jlo, n;
    if (backward) { jlo = i; n = min(WIDTH + 2, PAD - i); }
    else          { jlo = max(0, i - WIDTH - 1); n = i - jlo + 1; }

    const int s = lane >> 4;
    const int d = lane & 15;
    const size_t rowbase = (size_t)(b * PAD) * 1536;
    const int colq = h * DK;

    float4 q4 = *(const float4*)(QKV + rowbase + (size_t)i * 1536 + colq + 4 * d);

    float sc[5];
    #pragma unroll
    for (int m = 0; m < 5; ++m) {
        int t  = 4 * m + s;
        int tc = t < n ? t : n - 1;
        float4 kv = *(const float4*)(QKV + rowbase + (size_t)(jlo + tc) * 1536
                                     + 512 + colq + 4 * d);
        float p = q4.x * kv.x + q4.y * kv.y + q4.z * kv.z + q4.w * kv.w;
        p += __shfl_xor(p, 1);
        p += __shfl_xor(p, 2);
        p += __shfl_xor(p, 4);
        p += __shfl_xor(p, 8);
        sc[m] = p * 0.125f;
    }

    float sv[WIDTH + 2];
    #pragma unroll
    for (int t = 0; t < WIDTH + 2; ++t) {
        float v = __shfl(sc[t >> 2], (t & 3) << 4);
        sv[t] = (t < n) ? v : -1e30f;
    }
    float mx = sv[0];
    #pragma unroll
    for (int t = 1; t < WIDTH + 2; ++t) mx = fmaxf(mx, sv[t]);
    float denom = 0.f;
    #pragma unroll
    for (int t = 0; t < WIDTH + 2; ++t) { sv[t] = __expf(sv[t] - mx); denom += sv[t]; }
    float inv = 1.0f / denom;

    float od0 = 0.f, od1 = 0.f;
    #pragma unroll
    for (int t = 0; t < WIDTH + 2; t += 2) {
        int tc0 = t     < n ? t     : n - 1;
        int tc1 = t + 1 < n ? t + 1 : n - 1;
        od0 += sv[t]     * QKV[rowbase + (size_t)(jlo + tc0) * 1536 + 1024 + colq + lane];
        od1 += sv[t + 1] * QKV[rowbase + (size_t)(jlo + tc1) * 1536 + 1024 + colq + lane];
    }
    float od = (od0 + od1) * inv;

    unsigned short hh, ll;
    split2(od, hh, ll);
    size_t ro = (size_t)(b * PAD + i) * RS + colq + lane;
    O2[ro] = hh; O2[ro + 512] = ll;
}

// ---------------------------------------------------------------------------
// rel combine -> split acts
// ---------------------------------------------------------------------------
__global__ __launch_bounds__(256) void rel_combine(
    const float* __restrict__ a0, const float* __restrict__ a1,
    const float* __restrict__ w0, const float* __restrict__ w1,
    unsigned short* __restrict__ f0, unsigned short* __restrict__ f1,
    int off0, int off1)
{
    const float* att = blockIdx.z ? a1 : a0;
    const float* w   = blockIdx.z ? w1 : w0;
    unsigned short* fo2 = blockIdx.z ? f1 : f0;
    int offset = blockIdx.z ? off1 : off0;

    int idx = blockIdx.x * 256 + threadIdx.x;   // over B*S*128
    int c4 = idx & 127;
    int rest = idx >> 7;
    int t = rest & (S - 1);
    int b = rest >> 10;

    const float* rowbase = att + (size_t)b * PAD * HID + c4 * 4;
    float4 acc = *(const float4*)(rowbase + (size_t)(WIDTH + t) * HID);
    #pragma unroll
    for (int k = 0; k <= WIDTH; ++k) {
        float wk = w[k];
        float4 xv = *(const float4*)(rowbase + (size_t)(offset + k + t) * HID);
        acc.x += wk * xv.x; acc.y += wk * xv.y;
        acc.z += wk * xv.z; acc.w += wk * xv.w;
    }
    store_split4(fo2 + ((size_t)b * S + t) * RS + c4 * 4, acc);
}

// ---------------------------------------------------------------------------
// highway gate; x reconstructed from split acts (h+l)
// ---------------------------------------------------------------------------
__global__ __launch_bounds__(256) void highway_gate(
    const unsigned short* __restrict__ x0, const unsigned short* __restrict__ x1,
    const float* __restrict__ p0, const float* __restrict__ p1,
    float* __restrict__ of0, float* __restrict__ of1,
    unsigned short* __restrict__ o20, unsigned short* __restrict__ o21,
    float* __restrict__ os0, float* __restrict__ os1)
{
    const unsigned short* x2 = blockIdx.z ? x1 : x0;
    const float* proj        = blockIdx.z ? p1 : p0;
    float* outf              = blockIdx.z ? of1 : of0;
    unsigned short* out2     = blockIdx.z ? o21 : o20;
    float* oslice            = blockIdx.z ? os1 : os0;

    int idx = blockIdx.x * 256 + threadIdx.x;   // over B*S*128
    int c4 = idx & 127;
    int r  = idx >> 7;
    const unsigned short* xr = x2 + (size_t)r * RS + c4 * 4;
    uint2 hp = *(const uint2*)(xr);
    uint2 lp = *(const uint2*)(xr + 512);
    float4 xv;
    xv.x = bf2f((unsigned short)(hp.x & 0xffff)) + bf2f((unsigned short)(lp.x & 0xffff));
    xv.y = bf2f((unsigned short)(hp.x >> 16))    + bf2f((unsigned short)(lp.x >> 16));
    xv.z = bf2f((unsigned short)(hp.y & 0xffff)) + bf2f((unsigned short)(lp.y & 0xffff));
    xv.w = bf2f((unsigned short)(hp.y >> 16))    + bf2f((unsigned short)(lp.y >> 16));

    float4 nl = *(const float4*)(proj + (size_t)r * (2 * HID) + c4 * 4);
    float4 g  = *(const float4*)(proj + (size_t)r * (2 * HID) + HID + c4 * 4);
    float4 o;
    float sg;
    sg = 1.f / (1.f + __expf(-g.x)); o.x = sg * xv.x + (1.f - sg) * fmaxf(nl.x, 0.f);
    sg = 1.f / (1.f + __expf(-g.y)); o.y = sg * xv.y + (1.f - sg) * fmaxf(nl.y, 0.f);
    sg = 1.f / (1.f + __expf(-g.z)); o.z = sg * xv.z + (1.f - sg) * fmaxf(nl.z, 0.f);
    sg = 1.f / (1.f + __expf(-g.w)); o.w = sg * xv.w + (1.f - sg) * fmaxf(nl.w, 0.f);
    if (outf)   *(float4*)(outf + (size_t)idx * 4) = o;
    if (out2)   store_split4(out2 + (size_t)r * RS + c4 * 4, o);
    if (oslice) *(float4*)(oslice + (size_t)r * (2 * HID) + c4 * 4) = o;
}

// ---------------------------------------------------------------------------
extern "C" void kernel_launch(void* const* d_in, const int* in_sizes, int n_in,
                              void* d_out, int out_size, void* d_ws, size_t ws_size,
                              hipStream_t stream)
{
    const float* inputs   = (const float*)d_in[0];
    const float* fw_lin_w = (const float*)d_in[2];
    const float* fw_lin_b = (const float*)d_in[3];
    const float* bw_lin_w = (const float*)d_in[4];
    const float* bw_lin_b = (const float*)d_in[5];
    const float* fw_hw_w  = (const float*)d_in[6];
    const float* fw_hw_b  = (const float*)d_in[7];
    const float* bw_hw_w  = (const float*)d_in[8];
    const float* bw_hw_b  = (const float*)d_in[9];
    const float* fw_pad   = (const float*)d_in[10];
    const float* bw_pad   = (const float*)d_in[11];
    const float* fw_rel   = (const float*)d_in[12];
    const float* bw_rel   = (const float*)d_in[13];
    float* out = (float*)d_out;
    float* ws  = (float*)d_ws;

    const size_t BSH  = (size_t)B * S * HID;      // 2,097,152 floats
    const size_t QKVF = (size_t)B * PAD * 1536;   // 6,488,064 floats per dir
    const int MP = B * PAD;                       // 4224
    const int MS = B * S;                         // 4096

    const size_t GROUPED_BYTES = (size_t)18874368 * 4;
    const bool grouped = ws_size >= GROUPED_BYTES;
    const int G = grouped ? 2 : 1;

    float* f  = ws;
    float* bk = f + BSH;

    float* QKV[2]; float* ATT[2]; float* HWP[2];
    unsigned short* ACT2[2]; unsigned short* W2[2];
    if (grouped) {
        QKV[0] = ws;             QKV[1] = ws + QKVF;
        float* extra = ws + 2 * BSH;
        ATT[0] = extra;          ATT[1] = extra + (size_t)MP * HID;
        HWP[0] = extra;          HWP[1] = extra + (size_t)MS * 1024;
        unsigned short* a2 = (unsigned short*)(ws + 2 * QKVF);
        ACT2[0] = a2;            ACT2[1] = a2 + (size_t)MP * RS;
        unsigned short* w2 = a2 + 2 * (size_t)MP * RS;
        W2[0] = w2;              W2[1] = w2 + (size_t)1536 * RS;
    } else {
        float* qkvS = bk + BSH;
        QKV[0] = QKV[1] = qkvS;
        ATT[0] = ATT[1] = qkvS;
        HWP[0] = HWP[1] = qkvS;
        unsigned short* a2 = (unsigned short*)(qkvS + QKVF);
        ACT2[0] = ACT2[1] = a2;
        W2[0] = W2[1] = a2 + (size_t)MP * RS;
    }

    for (int l = 0; l < NLAYERS; ++l) {
        const float* LINW[2] = {fw_lin_w + (size_t)l * 4 * HID * HID,
                                bw_lin_w + (size_t)l * 4 * HID * HID};
        const float* LINB[2] = {fw_lin_b + (size_t)l * 4 * HID,
                                bw_lin_b + (size_t)l * 4 * HID};
        const float* HWW[2]  = {fw_hw_w + (size_t)l * NHW * 2 * HID * HID,
                                bw_hw_w + (size_t)l * NHW * 2 * HID * HID};
        const float* HWB[2]  = {fw_hw_b + (size_t)l * NHW * 2 * HID,
                                bw_hw_b + (size_t)l * NHW * 2 * HID};
        const float* RELW[2] = {fw_rel + (size_t)l * (WIDTH + 1),
                                bw_rel + (size_t)l * (WIDTH + 1)};
        const float* front = fw_pad + (size_t)l * WIDTH * HID;
        const float* back  = bw_pad + (size_t)l * WIDTH * HID;
        float* DST[2] = {f, bk};
        float* OSL[2] = {out + (size_t)l * B * S * 2 * HID,
                         out + (size_t)l * B * S * 2 * HID + HID};
        const float* SRC[2] = {(l == 0) ? inputs : f, (l == 0) ? inputs : bk};

        for (int d0 = 0; d0 < 2; d0 += G) {
            const int dB = (G == 2) ? 1 : d0;

            build_pad_split<<<dim3(MP * 128 / 256, 1, G), 256, 0, stream>>>(
                SRC[d0], SRC[dB], front, back, ACT2[0], ACT2[1]);

            conv_w<<<dim3(1536 * 128 / 256, 1, G), 256, 0, stream>>>(
                LINW[d0], LINW[dB], W2[0], W2[1]);
            gemm_split<<<dim3(1536 / 128, MP / 128, G), 256, 0, stream>>>(
                ACT2[0], W2[0], LINB[d0], QKV[0],
                ACT2[1], W2[1], LINB[dB], QKV[1], 1536);

            banded_attn<<<dim3(B * NHEADS * PAD / 4, 1, G), 256, 0, stream>>>(
                QKV[0], QKV[1], ACT2[0], ACT2[1], d0);

            conv_w<<<dim3(512 * 128 / 256, 1, G), 256, 0, stream>>>(
                LINW[d0] + 3 * (size_t)HID * HID, LINW[dB] + 3 * (size_t)HID * HID,
                W2[0], W2[1]);
            gemm_split<<<dim3(512 / 128, MP / 128, G), 256, 0, stream>>>(
                ACT2[0], W2[0], LINB[d0] + 3 * HID, ATT[0],
                ACT2[1], W2[1], LINB[dB] + 3 * HID, ATT[1], 512);

            rel_combine<<<dim3(MS * 128 / 256, 1, G), 256, 0, stream>>>(
                ATT[0], ATT[1], RELW[d0], RELW[dB], ACT2[0], ACT2[1],
                d0 * WIDTH, dB * WIDTH);

            for (int i = 0; i < NHW; ++i) {
                conv_w<<<dim3(1024 * 128 / 256, 1, G), 256, 0, stream>>>(
                    HWW[d0] + (size_t)i * 2 * HID * HID,
                    HWW[dB] + (size_t)i * 2 * HID * HID, W2[0], W2[1]);
                gemm_split<<<dim3(1024 / 128, MS / 128, G), 256, 0, stream>>>(
                    ACT2[0], W2[0], HWB[d0] + (size_t)i * 2 * HID, HWP[0],
                    ACT2[1], W2[1], HWB[dB] + (size_t)i * 2 * HID, HWP[1], 1024);
                const bool last = (i == NHW - 1);
                highway_gate<<<dim3(MS * 128 / 256, 1, G), 256, 0, stream>>>(
                    ACT2[0], ACT2[1], HWP[0], HWP[1],
                    last ? DST[d0] : (float*)nullptr,
                    last ? DST[dB] : (float*)nullptr,
                    last ? (unsigned short*)nullptr : ACT2[0],
                    last ? (unsigned short*)nullptr : ACT2[1],
                    last ? OSL[d0] : (float*)nullptr,
                    last ? OSL[dB] : (float*)nullptr);
            }
        }
    }
}